// Round 5
// baseline (226.776 us; speedup 1.0000x reference)
//
#include <hip/hip_runtime.h>

// Problem constants
#define BB 4
#define SS 2048
#define EE 640
#define NHH 10
#define DHH 64
#define MTOK 8192   // BB*SS
#define E33 1920

#define LDST 72     // LDS row stride (elements): 144B, 16B-aligned, bank-spreading

// exp2 intrinsic (native v_exp_f32)
#if __has_builtin(__builtin_amdgcn_exp2f)
#define EXP2(x) __builtin_amdgcn_exp2f(x)
#else
#define EXP2(x) exp2f(x)
#endif

#define QSCALE 0.18033688011112042f   // 0.125 * log2(e): folds softmax scale + exp->exp2 into Q

typedef float f32x4 __attribute__((ext_vector_type(4)));
typedef __bf16 bf16x8 __attribute__((ext_vector_type(8)));
typedef __bf16 bf16x4 __attribute__((ext_vector_type(4)));
typedef unsigned short u16;
typedef u16 u16x4 __attribute__((ext_vector_type(4)));

__device__ inline u16 f2bf(float f) {
  unsigned u = __builtin_bit_cast(unsigned, f);
  u += 0x7fffu + ((u >> 16) & 1u);   // round-to-nearest-even
  return (u16)(u >> 16);
}

// ---------------------------------------------------------------- convert
__global__ void convert_kernel(const float* __restrict__ in, u16* __restrict__ out, int n4) {
  int i = blockIdx.x * blockDim.x + threadIdx.x;
  if (i < n4) {
    float4 v = ((const float4*)in)[i];
    u16x4 o = { f2bf(v.x), f2bf(v.y), f2bf(v.z), f2bf(v.w) };
    ((u16x4*)out)[i] = o;
  }
}

// ---------------------------------------------------------------- QKV GEMM
// C[8192,1920] = A[8192,640] * Bt[1920,640]^T, scatter into q/k/v^T buffers.
// Q is pre-scaled by 0.125*log2e so the attention softmax runs in exp2 domain
// with no per-score multiply.
__global__ __launch_bounds__(256) void gemm_qkv(
    const u16* __restrict__ A, const u16* __restrict__ Bt,
    u16* __restrict__ qb, u16* __restrict__ kb, u16* __restrict__ vt) {
  __shared__ __align__(16) u16 As[128 * LDST];
  __shared__ __align__(16) u16 Bs[128 * LDST];
  const int t = threadIdx.x;
  const int m0 = blockIdx.y * 128;
  const int n0 = blockIdx.x * 128;
  const int w = t >> 6, lane = t & 63, n16 = lane & 15, quad = lane >> 4;
  const int wm = w >> 1, wn = w & 1;

  f32x4 acc[4][4];
  for (int i = 0; i < 4; i++)
    for (int j = 0; j < 4; j++) acc[i][j] = f32x4{0.f, 0.f, 0.f, 0.f};

  for (int kt = 0; kt < 10; ++kt) {       // K=640, BK=64
    __syncthreads();
    for (int i = 0; i < 4; ++i) {
      int c = i * 256 + t;
      int row = c >> 3, col0 = (c & 7) * 8;
      *(bf16x8*)&As[row * LDST + col0] = *(const bf16x8*)&A[(m0 + row) * 640 + kt * 64 + col0];
      *(bf16x8*)&Bs[row * LDST + col0] = *(const bf16x8*)&Bt[(n0 + row) * 640 + kt * 64 + col0];
    }
    __syncthreads();
    for (int ks = 0; ks < 2; ++ks) {
      bf16x8 a[4], b[4];
      for (int mi = 0; mi < 4; mi++)
        a[mi] = *(const bf16x8*)&As[(wm * 64 + mi * 16 + n16) * LDST + ks * 32 + quad * 8];
      for (int ni = 0; ni < 4; ni++)
        b[ni] = *(const bf16x8*)&Bs[(wn * 64 + ni * 16 + n16) * LDST + ks * 32 + quad * 8];
      for (int mi = 0; mi < 4; mi++)
        for (int ni = 0; ni < 4; ni++)
          acc[mi][ni] = __builtin_amdgcn_mfma_f32_16x16x32_bf16(a[mi], b[ni], acc[mi][ni], 0, 0, 0);
    }
  }

  // Epilogue: col e -> which = e/640 (uniform per block since 640 % 128 == 0)
  const int which = n0 / 640;
  for (int ni = 0; ni < 4; ni++) {
    int col = n0 + wn * 64 + ni * 16 + n16;
    int eh = col - which * 640;
    int h = eh >> 6, d = eh & 63;
    for (int mi = 0; mi < 4; mi++) {
      int tb = m0 + wm * 64 + mi * 16 + quad * 4;   // 4 consecutive tokens (r=0..3)
      f32x4 c = acc[mi][ni];
      if (which == 0) {   // uniform branch: pre-scale Q for exp2-domain softmax
        c[0] *= QSCALE; c[1] *= QSCALE; c[2] *= QSCALE; c[3] *= QSCALE;
      }
      if (which == 2) {
        // v^T[bh][d][s], 4 consecutive s -> packed 8B store
        int b_ = tb >> 11, s_ = tb & 2047;
        u16x4 pk = { f2bf(c[0]), f2bf(c[1]), f2bf(c[2]), f2bf(c[3]) };
        *(u16x4*)&vt[((b_ * NHH + h) * DHH + d) * SS + s_] = pk;
      } else {
        u16* dst = (which == 0) ? qb : kb;
        for (int r = 0; r < 4; r++) {
          int tok = tb + r;
          int b_ = tok >> 11, s_ = tok & 2047;
          dst[((b_ * NHH + h) * SS + s_) * DHH + d] = f2bf(c[r]);
        }
      }
    }
  }
}

// ---------------------------------------------------------------- attention
// One block: 64 q rows of one (b,h); 4 waves x 16 q rows.  S^T = K*Q^T trick:
// scores come out with col=lane&15=q, so softmax stats are per-lane scalars
// (2 shfls) and P^T is directly the B-operand of O^T = V^T*P^T.
// K staged in LDS (permuted rows, double-buffered, reg-staged prefetch).
// V is NOT staged: PV fragments load straight from global -- all 4 waves read
// the same 16B lines (L1 broadcast), and one bh's V (256KB) is L2-resident
// across its 32 q-blocks.  This halves LDS-pipe traffic per tile.
__global__ __launch_bounds__(256) void attn_kernel(
    const u16* __restrict__ qb, const u16* __restrict__ kb, const u16* __restrict__ vt,
    u16* __restrict__ y) {
  __shared__ __align__(16) u16 Ks[2][64 * LDST];   // K[perm(key)][d], double-buffered
  const int t = threadIdx.x;
  const int w = t >> 6, lane = t & 63, n16 = lane & 15, quad = lane >> 4;
  const int bh = blockIdx.x;
  const int qt = 31 - blockIdx.y;        // longest blocks first
  const int qb0 = qt * 64;
  const int b_ = bh / NHH, h = bh % NHH;

  // Q fragment (B-operand of S^T): B[n=q][k=d], q = qb0 + w*16 + n16
  bf16x8 aq[2];
  {
    const u16* qp = &qb[(bh * SS + qb0 + w * 16 + n16) * DHH];
    aq[0] = *(const bf16x8*)&qp[quad * 8];
    aq[1] = *(const bf16x8*)&qp[32 + quad * 8];
  }
  const int q_rel = w * 16 + n16;

  // K staging: each thread moves 2x16B per tile
  const int c1 = 256 + t;
  const int row0 = t >> 3,  col0 = (t & 7) * 8;
  const int row1 = c1 >> 3, col1 = (c1 & 7) * 8;
  // key -> permuted LDS row: key = p*32 + quad*8 + b*4 + r  ->  (2p+b)*16 + quad*4 + r
  auto perm = [](int k) {
    int p = k >> 5, rem = k & 31, qd = rem >> 3, tt = rem & 7;
    return ((p << 1) | (tt >> 2)) * 16 + qd * 4 + (tt & 3);
  };
  const int prow0 = perm(row0), prow1 = perm(row1);

  float4 fk0, fk1;
  fk0 = *(const float4*)&kb[(bh * SS + row0) * DHH + col0];
  fk1 = *(const float4*)&kb[(bh * SS + row1) * DHH + col1];
  *(float4*)&Ks[0][prow0 * LDST + col0] = fk0;
  *(float4*)&Ks[0][prow1 * LDST + col1] = fk1;

  // V fragment base: d = db*16 + n16 (row), col = kk + p2*32 + quad*8
  const u16* vbase = &vt[((size_t)bh * DHH + n16) * SS + quad * 8];

  float m_i = -1e30f, l_i = 0.f;
  f32x4 o[4];
  for (int db = 0; db < 4; db++) o[db] = f32x4{0.f, 0.f, 0.f, 0.f};

  for (int kt = 0; kt <= qt; ++kt) {
    __syncthreads();
    const int cur = kt & 1, nxt = cur ^ 1;
    const int kk = kt * 64;

    // V fragments for the CURRENT tile, direct from global (consumed after
    // QK^T + softmax, several hundred cycles of latency hiding)
    bf16x8 av[2][4];
#pragma unroll
    for (int p2 = 0; p2 < 2; p2++)
#pragma unroll
      for (int db = 0; db < 4; db++)
        av[p2][db] = *(const bf16x8*)&vbase[(size_t)db * 16 * SS + kk + p2 * 32];

    if (kt < qt) {   // prefetch next K tile into registers
      fk0 = *(const float4*)&kb[(bh * SS + kk + 64 + row0) * DHH + col0];
      fk1 = *(const float4*)&kb[(bh * SS + kk + 64 + row1) * DHH + col1];
    }

    // S^T = K * Q^T : A=K (m=permuted key), B=Q (n=q); log2-domain scores
    f32x4 sc[4];
#pragma unroll
    for (int nb = 0; nb < 4; nb++) {
      f32x4 c = f32x4{0.f, 0.f, 0.f, 0.f};
      bf16x8 ak0 = *(const bf16x8*)&Ks[cur][(nb * 16 + n16) * LDST + quad * 8];
      c = __builtin_amdgcn_mfma_f32_16x16x32_bf16(ak0, aq[0], c, 0, 0, 0);
      bf16x8 ak1 = *(const bf16x8*)&Ks[cur][(nb * 16 + n16) * LDST + 32 + quad * 8];
      c = __builtin_amdgcn_mfma_f32_16x16x32_bf16(ak1, aq[1], c, 0, 0, 0);
      sc[nb] = c;
    }

    // causal mask only on the diagonal tile (uniform branch)
    if (kt == qt) {
#pragma unroll
      for (int nb = 0; nb < 4; nb++)
#pragma unroll
        for (int r = 0; r < 4; r++) {
          int key = ((nb >> 1) << 5) + quad * 8 + ((nb & 1) << 2) + r;
          if (key > q_rel) sc[nb][r] = -1e30f;
        }
    }

    // tile max (tree, v_max3-friendly), replicated over the 4 quads
    f32x4 mx;
#pragma unroll
    for (int r = 0; r < 4; r++)
      mx[r] = fmaxf(fmaxf(sc[0][r], sc[1][r]), fmaxf(sc[2][r], sc[3][r]));
    float rm = fmaxf(fmaxf(mx[0], mx[1]), fmaxf(mx[2], mx[3]));
    rm = fmaxf(rm, __shfl_xor(rm, 16));
    rm = fmaxf(rm, __shfl_xor(rm, 32));

    // T13 defer-max: skip the O/l rescale unless some lane's max grew by >8
    if (!__all(rm - m_i <= 8.0f)) {
      float mnew = fmaxf(m_i, rm);
      float alpha = EXP2(m_i - mnew);
      l_i *= alpha;
#pragma unroll
      for (int db = 0; db < 4; db++)
#pragma unroll
        for (int r = 0; r < 4; r++) o[db][r] *= alpha;
      m_i = mnew;
    }

    // P = 2^(S - m): 16 sub + 16 v_exp, row-sum via tree
    f32x4 ps[4];
#pragma unroll
    for (int nb = 0; nb < 4; nb++)
#pragma unroll
      for (int r = 0; r < 4; r++) ps[nb][r] = EXP2(sc[nb][r] - m_i);
    f32x4 sv;
#pragma unroll
    for (int r = 0; r < 4; r++)
      sv[r] = (ps[0][r] + ps[1][r]) + (ps[2][r] + ps[3][r]);
    float rs = (sv[0] + sv[1]) + (sv[2] + sv[3]);
    rs += __shfl_xor(rs, 16);
    rs += __shfl_xor(rs, 32);
    l_i += rs;

    // O^T += V^T * P^T : A=V^T (from global), B=P^T (n=q, k=key)
#pragma unroll
    for (int p2 = 0; p2 < 2; p2++) {
      bf16x8 bp;
#pragma unroll
      for (int j = 0; j < 4; j++) {
        bp[j]     = (__bf16)ps[2 * p2][j];
        bp[4 + j] = (__bf16)ps[2 * p2 + 1][j];
      }
#pragma unroll
      for (int db = 0; db < 4; db++)
        o[db] = __builtin_amdgcn_mfma_f32_16x16x32_bf16(av[p2][db], bp, o[db], 0, 0, 0);
    }

    if (kt < qt) {   // write prefetched K tile into the other buffer
      *(float4*)&Ks[nxt][prow0 * LDST + col0] = fk0;
      *(float4*)&Ks[nxt][prow1 * LDST + col1] = fk1;
    }
  }

  // epilogue: O^T[d][q] -> y[token][h*64+d]; lane owns q = q_rel, d = db*16+quad*4+r
  const float inv = 1.0f / l_i;
  const int tok = b_ * SS + qb0 + w * 16 + n16;
#pragma unroll
  for (int db = 0; db < 4; db++) {
    bf16x4 pk = { (__bf16)(o[db][0] * inv), (__bf16)(o[db][1] * inv),
                  (__bf16)(o[db][2] * inv), (__bf16)(o[db][3] * inv) };
    *(bf16x4*)&y[tok * EE + h * DHH + db * 16 + quad * 4] = pk;
  }
}

// ---------------------------------------------------------------- proj GEMM
// out[8192,640] fp32 = y[8192,640] * wproj[640,640]^T
__global__ __launch_bounds__(256) void gemm_proj(
    const u16* __restrict__ A, const u16* __restrict__ Bt, float* __restrict__ out) {
  __shared__ __align__(16) u16 As[128 * LDST];
  __shared__ __align__(16) u16 Bs[128 * LDST];
  const int t = threadIdx.x;
  const int m0 = blockIdx.y * 128;
  const int n0 = blockIdx.x * 128;
  const int w = t >> 6, lane = t & 63, n16 = lane & 15, quad = lane >> 4;
  const int wm = w >> 1, wn = w & 1;

  f32x4 acc[4][4];
  for (int i = 0; i < 4; i++)
    for (int j = 0; j < 4; j++) acc[i][j] = f32x4{0.f, 0.f, 0.f, 0.f};

  for (int kt = 0; kt < 10; ++kt) {
    __syncthreads();
    for (int i = 0; i < 4; ++i) {
      int c = i * 256 + t;
      int row = c >> 3, col0 = (c & 7) * 8;
      *(bf16x8*)&As[row * LDST + col0] = *(const bf16x8*)&A[(m0 + row) * 640 + kt * 64 + col0];
      *(bf16x8*)&Bs[row * LDST + col0] = *(const bf16x8*)&Bt[(n0 + row) * 640 + kt * 64 + col0];
    }
    __syncthreads();
    for (int ks = 0; ks < 2; ++ks) {
      bf16x8 a[4], b[4];
      for (int mi = 0; mi < 4; mi++)
        a[mi] = *(const bf16x8*)&As[(wm * 64 + mi * 16 + n16) * LDST + ks * 32 + quad * 8];
      for (int ni = 0; ni < 4; ni++)
        b[ni] = *(const bf16x8*)&Bs[(wn * 64 + ni * 16 + n16) * LDST + ks * 32 + quad * 8];
      for (int mi = 0; mi < 4; mi++)
        for (int ni = 0; ni < 4; ni++)
          acc[mi][ni] = __builtin_amdgcn_mfma_f32_16x16x32_bf16(a[mi], b[ni], acc[mi][ni], 0, 0, 0);
    }
  }

  for (int ni = 0; ni < 4; ni++) {
    int col = n0 + wn * 64 + ni * 16 + n16;
    for (int mi = 0; mi < 4; mi++) {
      int rowb = m0 + wm * 64 + mi * 16 + quad * 4;
      f32x4 c = acc[mi][ni];
      for (int r = 0; r < 4; r++) out[(rowb + r) * 640 + col] = c[r];
    }
  }
}

// ---------------------------------------------------------------- launch
extern "C" void kernel_launch(void* const* d_in, const int* in_sizes, int n_in,
                              void* d_out, int out_size, void* d_ws, size_t ws_size,
                              hipStream_t stream) {
  const float* x     = (const float*)d_in[0];   // [4,2048,640]
  const float* wqkv  = (const float*)d_in[1];   // [1920,640]
  const float* wproj = (const float*)d_in[2];   // [640,640]
  float* out = (float*)d_out;

  char* ws = (char*)d_ws;
  u16* xb     = (u16*)(ws + 0);            // 10,485,760 B
  u16* wqkvb  = (u16*)(ws + 10485760);     //  2,457,600 B
  u16* wprojb = (u16*)(ws + 12943360);     //    819,200 B
  u16* qbuf   = (u16*)(ws + 13762560);     // 10,485,760 B  [bh][s][d]
  u16* kbuf   = (u16*)(ws + 24248320);     // 10,485,760 B  [bh][s][d]
  u16* vtb    = (u16*)(ws + 34734080);     // 10,485,760 B  [bh][d][s]
  u16* ybuf   = (u16*)(ws + 45219840);     // 10,485,760 B  [tok][e]

  convert_kernel<<<5120, 256, 0, stream>>>(x, xb, 5242880 / 4);
  convert_kernel<<<1200, 256, 0, stream>>>(wqkv, wqkvb, 1228800 / 4);
  convert_kernel<<<400, 256, 0, stream>>>(wproj, wprojb, 409600 / 4);

  gemm_qkv<<<dim3(15, 64), 256, 0, stream>>>(xb, wqkvb, qbuf, kbuf, vtb);
  attn_kernel<<<dim3(40, 32), 256, 0, stream>>>(qbuf, kbuf, vtb, ybuf);
  gemm_proj<<<dim3(5, 64), 256, 0, stream>>>(ybuf, wprojb, out);
}

// Round 6
// 173.550 us; speedup vs baseline: 1.3067x; 1.3067x over previous
//
#include <hip/hip_runtime.h>

// Problem constants
#define BB 4
#define SS 2048
#define EE 640
#define NHH 10
#define DHH 64
#define MTOK 8192   // BB*SS
#define E33 1920

#define LDST 72     // LDS row stride (elements): 144B, 16B-aligned, bank-spreading

// exp2 intrinsic (native v_exp_f32)
#if __has_builtin(__builtin_amdgcn_exp2f)
#define EXP2(x) __builtin_amdgcn_exp2f(x)
#else
#define EXP2(x) exp2f(x)
#endif

#define QSCALE 0.18033688011112042f   // 0.125 * log2(e): folds softmax scale + exp->exp2 into Q

typedef float f32x4 __attribute__((ext_vector_type(4)));
typedef __bf16 bf16x8 __attribute__((ext_vector_type(8)));
typedef __bf16 bf16x4 __attribute__((ext_vector_type(4)));
typedef unsigned short u16;
typedef u16 u16x4 __attribute__((ext_vector_type(4)));

__device__ inline u16 f2bf(float f) {
  unsigned u = __builtin_bit_cast(unsigned, f);
  u += 0x7fffu + ((u >> 16) & 1u);   // round-to-nearest-even
  return (u16)(u >> 16);
}

// ---------------------------------------------------------------- convert
// All three fp32->bf16 conversions in ONE launch (saves 2 launches + gaps).
#define XN4   1310720   // 4*2048*640 / 4
#define WQN4   307200   // 1920*640 / 4
#define WPN4   102400   // 640*640 / 4
__global__ void convert_all(const float* __restrict__ x, const float* __restrict__ wqkv,
                            const float* __restrict__ wproj,
                            u16* __restrict__ xb, u16* __restrict__ wqkvb,
                            u16* __restrict__ wprojb) {
  int i = blockIdx.x * blockDim.x + threadIdx.x;
  const float* src; u16* dst; int off;
  if (i < XN4)              { src = x;     dst = xb;     off = i; }
  else if (i < XN4 + WQN4)  { src = wqkv;  dst = wqkvb;  off = i - XN4; }
  else if (i < XN4 + WQN4 + WPN4) { src = wproj; dst = wprojb; off = i - XN4 - WQN4; }
  else return;
  float4 v = ((const float4*)src)[off];
  u16x4 o = { f2bf(v.x), f2bf(v.y), f2bf(v.z), f2bf(v.w) };
  ((u16x4*)dst)[off] = o;
}

// ---------------------------------------------------------------- QKV GEMM
// C[8192,1920] = A[8192,640] * Bt[1920,640]^T, scatter into q/k/v^T buffers.
// K-tile kt+1 is prefetched into REGISTERS while tile kt computes (the R1-attn
// pattern): global latency hides under the MFMA phase instead of being
// serialized into every K-step's load->ds_write round trip.
// Q is pre-scaled by 0.125*log2e so attention softmax runs in exp2 domain.
__global__ __launch_bounds__(256) void gemm_qkv(
    const u16* __restrict__ A, const u16* __restrict__ Bt,
    u16* __restrict__ qb, u16* __restrict__ kb, u16* __restrict__ vt) {
  __shared__ __align__(16) u16 As[128 * LDST];
  __shared__ __align__(16) u16 Bs[128 * LDST];
  const int t = threadIdx.x;
  const int m0 = blockIdx.y * 128;
  const int n0 = blockIdx.x * 128;
  const int w = t >> 6, lane = t & 63, n16 = lane & 15, quad = lane >> 4;
  const int wm = w >> 1, wn = w & 1;

  f32x4 acc[4][4];
  for (int i = 0; i < 4; i++)
    for (int j = 0; j < 4; j++) acc[i][j] = f32x4{0.f, 0.f, 0.f, 0.f};

  // prefetch K-tile 0 into registers
  bf16x8 pa[4], pb[4];
#pragma unroll
  for (int i = 0; i < 4; ++i) {
    int c = i * 256 + t, row = c >> 3, col0 = (c & 7) * 8;
    pa[i] = *(const bf16x8*)&A[(m0 + row) * 640 + col0];
    pb[i] = *(const bf16x8*)&Bt[(n0 + row) * 640 + col0];
  }

  for (int kt = 0; kt < 10; ++kt) {       // K=640, BK=64
    __syncthreads();                      // previous tile's readers done
#pragma unroll
    for (int i = 0; i < 4; ++i) {
      int c = i * 256 + t, row = c >> 3, col0 = (c & 7) * 8;
      *(bf16x8*)&As[row * LDST + col0] = pa[i];
      *(bf16x8*)&Bs[row * LDST + col0] = pb[i];
    }
    __syncthreads();
    if (kt < 9) {                         // prefetch next tile (hidden by MFMAs)
#pragma unroll
      for (int i = 0; i < 4; ++i) {
        int c = i * 256 + t, row = c >> 3, col0 = (c & 7) * 8;
        pa[i] = *(const bf16x8*)&A[(m0 + row) * 640 + (kt + 1) * 64 + col0];
        pb[i] = *(const bf16x8*)&Bt[(n0 + row) * 640 + (kt + 1) * 64 + col0];
      }
    }
#pragma unroll
    for (int ks = 0; ks < 2; ++ks) {
      bf16x8 a[4], b[4];
      for (int mi = 0; mi < 4; mi++)
        a[mi] = *(const bf16x8*)&As[(wm * 64 + mi * 16 + n16) * LDST + ks * 32 + quad * 8];
      for (int ni = 0; ni < 4; ni++)
        b[ni] = *(const bf16x8*)&Bs[(wn * 64 + ni * 16 + n16) * LDST + ks * 32 + quad * 8];
      for (int mi = 0; mi < 4; mi++)
        for (int ni = 0; ni < 4; ni++)
          acc[mi][ni] = __builtin_amdgcn_mfma_f32_16x16x32_bf16(a[mi], b[ni], acc[mi][ni], 0, 0, 0);
    }
  }

  // Epilogue: col e -> which = e/640 (uniform per block since 640 % 128 == 0)
  const int which = n0 / 640;
  for (int ni = 0; ni < 4; ni++) {
    int col = n0 + wn * 64 + ni * 16 + n16;
    int eh = col - which * 640;
    int h = eh >> 6, d = eh & 63;
    for (int mi = 0; mi < 4; mi++) {
      int tb = m0 + wm * 64 + mi * 16 + quad * 4;   // 4 consecutive tokens (r=0..3)
      f32x4 c = acc[mi][ni];
      if (which == 0) {   // uniform branch: pre-scale Q for exp2-domain softmax
        c[0] *= QSCALE; c[1] *= QSCALE; c[2] *= QSCALE; c[3] *= QSCALE;
      }
      if (which == 2) {
        // v^T[bh][d][s], 4 consecutive s -> packed 8B store
        int b_ = tb >> 11, s_ = tb & 2047;
        u16x4 pk = { f2bf(c[0]), f2bf(c[1]), f2bf(c[2]), f2bf(c[3]) };
        *(u16x4*)&vt[((b_ * NHH + h) * DHH + d) * SS + s_] = pk;
      } else {
        u16* dst = (which == 0) ? qb : kb;
        for (int r = 0; r < 4; r++) {
          int tok = tb + r;
          int b_ = tok >> 11, s_ = tok & 2047;
          dst[((b_ * NHH + h) * SS + s_) * DHH + d] = f2bf(c[r]);
        }
      }
    }
  }
}

// ---------------------------------------------------------------- attention
// One block: 64 q rows of one (b,h); 4 waves x 16 q rows.  (R1-exact, 49us.)
// S^T = K*Q^T trick: scores come out with col=lane&15=q, so softmax stats are
// per-lane scalars (2 shfls) and P^T is directly the B-operand of O^T = V^T*P^T.
// K rows staged permuted so the lane's 16 score regs enumerate keys in the
// K=32 B-frag pattern.  Softmax in log2 domain (scale folded into Q);
// T13 defer-max skips the O-rescale; K/V double-buffered with one-tile-ahead
// register prefetch (the latency hider -- R5 proved removing it costs 2x).
__global__ __launch_bounds__(256) void attn_kernel(
    const u16* __restrict__ qb, const u16* __restrict__ kb, const u16* __restrict__ vt,
    u16* __restrict__ y) {
  __shared__ __align__(16) u16 Ks[2][64 * LDST];   // K[perm(key)][d], double-buffered
  __shared__ __align__(16) u16 Vs[2][64 * LDST];   // V^T[d][key]
  const int t = threadIdx.x;
  const int w = t >> 6, lane = t & 63, n16 = lane & 15, quad = lane >> 4;
  const int bh = blockIdx.x;
  const int qt = 31 - blockIdx.y;        // longest blocks first
  const int qb0 = qt * 64;
  const int b_ = bh / NHH, h = bh % NHH;

  // Q fragment (B-operand of S^T): B[n=q][k=d], q = qb0 + w*16 + n16
  bf16x8 aq[2];
  {
    const u16* qp = &qb[(bh * SS + qb0 + w * 16 + n16) * DHH];
    aq[0] = *(const bf16x8*)&qp[quad * 8];
    aq[1] = *(const bf16x8*)&qp[32 + quad * 8];
  }
  const int q_rel = w * 16 + n16;

  // staging: each thread moves 2x16B of K and 2x16B of V per tile
  const int c1 = 256 + t;
  const int row0 = t >> 3,  col0 = (t & 7) * 8;
  const int row1 = c1 >> 3, col1 = (c1 & 7) * 8;
  // key -> permuted LDS row: key = p*32 + quad*8 + b*4 + r  ->  (2p+b)*16 + quad*4 + r
  auto perm = [](int k) {
    int p = k >> 5, rem = k & 31, qd = rem >> 3, tt = rem & 7;
    return ((p << 1) | (tt >> 2)) * 16 + qd * 4 + (tt & 3);
  };
  const int prow0 = perm(row0), prow1 = perm(row1);

  float4 fk0, fk1, fv0, fv1;
  fk0 = *(const float4*)&kb[(bh * SS + row0) * DHH + col0];
  fk1 = *(const float4*)&kb[(bh * SS + row1) * DHH + col1];
  fv0 = *(const float4*)&vt[(bh * DHH + row0) * SS + col0];
  fv1 = *(const float4*)&vt[(bh * DHH + row1) * SS + col1];
  *(float4*)&Ks[0][prow0 * LDST + col0] = fk0;
  *(float4*)&Ks[0][prow1 * LDST + col1] = fk1;
  *(float4*)&Vs[0][row0 * LDST + col0] = fv0;
  *(float4*)&Vs[0][row1 * LDST + col1] = fv1;

  float m_i = -1e30f, l_i = 0.f;
  f32x4 o[4];
  for (int db = 0; db < 4; db++) o[db] = f32x4{0.f, 0.f, 0.f, 0.f};

  for (int kt = 0; kt <= qt; ++kt) {
    __syncthreads();
    const int cur = kt & 1, nxt = cur ^ 1;
    if (kt < qt) {   // prefetch next tile (latency hidden behind compute)
      int kk = (kt + 1) * 64;
      fk0 = *(const float4*)&kb[(bh * SS + kk + row0) * DHH + col0];
      fk1 = *(const float4*)&kb[(bh * SS + kk + row1) * DHH + col1];
      fv0 = *(const float4*)&vt[(bh * DHH + row0) * SS + kk + col0];
      fv1 = *(const float4*)&vt[(bh * DHH + row1) * SS + kk + col1];
    }

    // S^T = K * Q^T : A=K (m=permuted key), B=Q (n=q); log2-domain scores
    f32x4 sc[4];
#pragma unroll
    for (int nb = 0; nb < 4; nb++) {
      f32x4 c = f32x4{0.f, 0.f, 0.f, 0.f};
      bf16x8 ak0 = *(const bf16x8*)&Ks[cur][(nb * 16 + n16) * LDST + quad * 8];
      c = __builtin_amdgcn_mfma_f32_16x16x32_bf16(ak0, aq[0], c, 0, 0, 0);
      bf16x8 ak1 = *(const bf16x8*)&Ks[cur][(nb * 16 + n16) * LDST + 32 + quad * 8];
      c = __builtin_amdgcn_mfma_f32_16x16x32_bf16(ak1, aq[1], c, 0, 0, 0);
      sc[nb] = c;
    }

    // causal mask only on the diagonal tile (uniform branch)
    if (kt == qt) {
#pragma unroll
      for (int nb = 0; nb < 4; nb++)
#pragma unroll
        for (int r = 0; r < 4; r++) {
          int key = ((nb >> 1) << 5) + quad * 8 + ((nb & 1) << 2) + r;
          if (key > q_rel) sc[nb][r] = -1e30f;
        }
    }

    // tile max (tree, v_max3-friendly), replicated over the 4 quads
    f32x4 mx;
#pragma unroll
    for (int r = 0; r < 4; r++)
      mx[r] = fmaxf(fmaxf(sc[0][r], sc[1][r]), fmaxf(sc[2][r], sc[3][r]));
    float rm = fmaxf(fmaxf(mx[0], mx[1]), fmaxf(mx[2], mx[3]));
    rm = fmaxf(rm, __shfl_xor(rm, 16));
    rm = fmaxf(rm, __shfl_xor(rm, 32));

    // T13 defer-max: skip the O/l rescale unless some lane's max grew by >8
    if (!__all(rm - m_i <= 8.0f)) {
      float mnew = fmaxf(m_i, rm);
      float alpha = EXP2(m_i - mnew);
      l_i *= alpha;
#pragma unroll
      for (int db = 0; db < 4; db++)
#pragma unroll
        for (int r = 0; r < 4; r++) o[db][r] *= alpha;
      m_i = mnew;
    }

    // P = 2^(S - m): 16 sub + 16 v_exp, row-sum via tree
    f32x4 ps[4];
#pragma unroll
    for (int nb = 0; nb < 4; nb++)
#pragma unroll
      for (int r = 0; r < 4; r++) ps[nb][r] = EXP2(sc[nb][r] - m_i);
    f32x4 sv;
#pragma unroll
    for (int r = 0; r < 4; r++)
      sv[r] = (ps[0][r] + ps[1][r]) + (ps[2][r] + ps[3][r]);
    float rs = (sv[0] + sv[1]) + (sv[2] + sv[3]);
    rs += __shfl_xor(rs, 16);
    rs += __shfl_xor(rs, 32);
    l_i += rs;

    // O^T += V^T * P^T : A=V^T (m=d), B=P^T (n=q, k=key) -- P already in B layout
#pragma unroll
    for (int p2 = 0; p2 < 2; p2++) {
      bf16x8 bp;
#pragma unroll
      for (int j = 0; j < 4; j++) {
        bp[j]     = (__bf16)ps[2 * p2][j];
        bp[4 + j] = (__bf16)ps[2 * p2 + 1][j];
      }
#pragma unroll
      for (int db = 0; db < 4; db++) {
        bf16x8 av = *(const bf16x8*)&Vs[cur][(db * 16 + n16) * LDST + p2 * 32 + quad * 8];
        o[db] = __builtin_amdgcn_mfma_f32_16x16x32_bf16(av, bp, o[db], 0, 0, 0);
      }
    }

    if (kt < qt) {   // write prefetched tile into the other buffer
      *(float4*)&Ks[nxt][prow0 * LDST + col0] = fk0;
      *(float4*)&Ks[nxt][prow1 * LDST + col1] = fk1;
      *(float4*)&Vs[nxt][row0 * LDST + col0] = fv0;
      *(float4*)&Vs[nxt][row1 * LDST + col1] = fv1;
    }
  }

  // epilogue: O^T[d][q] -> y[token][h*64+d]; lane owns q = q_rel, d = db*16+quad*4+r
  const float inv = 1.0f / l_i;
  const int tok = b_ * SS + qb0 + w * 16 + n16;
#pragma unroll
  for (int db = 0; db < 4; db++) {
    bf16x4 pk = { (__bf16)(o[db][0] * inv), (__bf16)(o[db][1] * inv),
                  (__bf16)(o[db][2] * inv), (__bf16)(o[db][3] * inv) };
    *(bf16x4*)&y[tok * EE + h * DHH + db * 16 + quad * 4] = pk;
  }
}

// ---------------------------------------------------------------- proj GEMM
// out[8192,640] fp32 = y[8192,640] * wproj[640,640]^T  (same reg-prefetch staging)
__global__ __launch_bounds__(256) void gemm_proj(
    const u16* __restrict__ A, const u16* __restrict__ Bt, float* __restrict__ out) {
  __shared__ __align__(16) u16 As[128 * LDST];
  __shared__ __align__(16) u16 Bs[128 * LDST];
  const int t = threadIdx.x;
  const int m0 = blockIdx.y * 128;
  const int n0 = blockIdx.x * 128;
  const int w = t >> 6, lane = t & 63, n16 = lane & 15, quad = lane >> 4;
  const int wm = w >> 1, wn = w & 1;

  f32x4 acc[4][4];
  for (int i = 0; i < 4; i++)
    for (int j = 0; j < 4; j++) acc[i][j] = f32x4{0.f, 0.f, 0.f, 0.f};

  bf16x8 pa[4], pb[4];
#pragma unroll
  for (int i = 0; i < 4; ++i) {
    int c = i * 256 + t, row = c >> 3, col0 = (c & 7) * 8;
    pa[i] = *(const bf16x8*)&A[(m0 + row) * 640 + col0];
    pb[i] = *(const bf16x8*)&Bt[(n0 + row) * 640 + col0];
  }

  for (int kt = 0; kt < 10; ++kt) {
    __syncthreads();
#pragma unroll
    for (int i = 0; i < 4; ++i) {
      int c = i * 256 + t, row = c >> 3, col0 = (c & 7) * 8;
      *(bf16x8*)&As[row * LDST + col0] = pa[i];
      *(bf16x8*)&Bs[row * LDST + col0] = pb[i];
    }
    __syncthreads();
    if (kt < 9) {
#pragma unroll
      for (int i = 0; i < 4; ++i) {
        int c = i * 256 + t, row = c >> 3, col0 = (c & 7) * 8;
        pa[i] = *(const bf16x8*)&A[(m0 + row) * 640 + (kt + 1) * 64 + col0];
        pb[i] = *(const bf16x8*)&Bt[(n0 + row) * 640 + (kt + 1) * 64 + col0];
      }
    }
#pragma unroll
    for (int ks = 0; ks < 2; ++ks) {
      bf16x8 a[4], b[4];
      for (int mi = 0; mi < 4; mi++)
        a[mi] = *(const bf16x8*)&As[(wm * 64 + mi * 16 + n16) * LDST + ks * 32 + quad * 8];
      for (int ni = 0; ni < 4; ni++)
        b[ni] = *(const bf16x8*)&Bs[(wn * 64 + ni * 16 + n16) * LDST + ks * 32 + quad * 8];
      for (int mi = 0; mi < 4; mi++)
        for (int ni = 0; ni < 4; ni++)
          acc[mi][ni] = __builtin_amdgcn_mfma_f32_16x16x32_bf16(a[mi], b[ni], acc[mi][ni], 0, 0, 0);
    }
  }

  for (int ni = 0; ni < 4; ni++) {
    int col = n0 + wn * 64 + ni * 16 + n16;
    for (int mi = 0; mi < 4; mi++) {
      int rowb = m0 + wm * 64 + mi * 16 + quad * 4;
      f32x4 c = acc[mi][ni];
      for (int r = 0; r < 4; r++) out[(rowb + r) * 640 + col] = c[r];
    }
  }
}

// ---------------------------------------------------------------- launch
extern "C" void kernel_launch(void* const* d_in, const int* in_sizes, int n_in,
                              void* d_out, int out_size, void* d_ws, size_t ws_size,
                              hipStream_t stream) {
  const float* x     = (const float*)d_in[0];   // [4,2048,640]
  const float* wqkv  = (const float*)d_in[1];   // [1920,640]
  const float* wproj = (const float*)d_in[2];   // [640,640]
  float* out = (float*)d_out;

  char* ws = (char*)d_ws;
  u16* xb     = (u16*)(ws + 0);            // 10,485,760 B
  u16* wqkvb  = (u16*)(ws + 10485760);     //  2,457,600 B
  u16* wprojb = (u16*)(ws + 12943360);     //    819,200 B
  u16* qbuf   = (u16*)(ws + 13762560);     // 10,485,760 B  [bh][s][d]
  u16* kbuf   = (u16*)(ws + 24248320);     // 10,485,760 B  [bh][s][d]
  u16* vtb    = (u16*)(ws + 34734080);     // 10,485,760 B  [bh][d][s]
  u16* ybuf   = (u16*)(ws + 45219840);     // 10,485,760 B  [tok][e]

  convert_all<<<6720, 256, 0, stream>>>(x, wqkv, wproj, xb, wqkvb, wprojb);

  gemm_qkv<<<dim3(15, 64), 256, 0, stream>>>(xb, wqkvb, qbuf, kbuf, vtb);
  attn_kernel<<<dim3(40, 32), 256, 0, stream>>>(qbuf, kbuf, vtb, ybuf);
  gemm_proj<<<dim3(5, 64), 256, 0, stream>>>(ybuf, wprojb, out);
}